// Round 1
// baseline (409.794 us; speedup 1.0000x reference)
//
#include <hip/hip_runtime.h>

typedef __bf16 bf16x8 __attribute__((ext_vector_type(8)));
typedef float  f32x4  __attribute__((ext_vector_type(4)));

// ws layout (bf16 elements), all in MFMA b-fragment order [kstep][ntile][lane][8]
#define OFF_W1  0        // 20 ksteps * 16 nt * 512  = 163840   (s_w1 640x256)
#define OFF_W2  163840   //  8 * 16 * 512            =  65536   (s_w2 256x256)
#define OFF_WQ  229376   //  8 *  8 * 512            =  32768   (qd|qe interleaved 256x128)
#define OFF_WH1 262144   //  1 *  8 * 512            =   4096   (h_w1 10->32 zero-pad x128)
#define OFF_WH2 266240   //  4 *  8 * 512            =  16384   (h_w2 128x128)
#define WS_ELEMS 282624

__global__ __launch_bounds__(256) void prep_kernel(
    const float* __restrict__ s_w1, const float* __restrict__ s_w2,
    const float* __restrict__ qd_w, const float* __restrict__ qe_w,
    const float* __restrict__ h_w1, const float* __restrict__ h_w2,
    __bf16* __restrict__ wsb)
{
  int idx = blockIdx.x * 256 + threadIdx.x;
  if (idx >= WS_ELEMS) return;
  float val = 0.f;
  if (idx < OFF_W2) {                       // W1: K=640, N=256
    int t = idx;
    int j = t & 7, l = (t >> 3) & 63, rest = t >> 9;
    int nt = rest & 15, ks = rest >> 4;
    int k = ks * 32 + (l >> 4) * 8 + j, n = nt * 16 + (l & 15);
    val = s_w1[k * 256 + n];
  } else if (idx < OFF_WQ) {                // W2: K=256, N=256
    int t = idx - OFF_W2;
    int j = t & 7, l = (t >> 3) & 63, rest = t >> 9;
    int nt = rest & 15, ks = rest >> 4;
    int k = ks * 32 + (l >> 4) * 8 + j, n = nt * 16 + (l & 15);
    val = s_w2[k * 256 + n];
  } else if (idx < OFF_WH1) {               // Wq: K=256, N=128, n = 2a+sel
    int t = idx - OFF_WQ;
    int j = t & 7, l = (t >> 3) & 63, rest = t >> 9;
    int nt = rest & 7, ks = rest >> 3;
    int k = ks * 32 + (l >> 4) * 8 + j, n = nt * 16 + (l & 15);
    int a = n >> 1;
    val = (n & 1) ? qe_w[k * 64 + a] : qd_w[k * 64 + a];
  } else if (idx < OFF_WH2) {               // Wh1: K=10 padded to 32, N=128
    int t = idx - OFF_WH1;
    int j = t & 7, l = (t >> 3) & 63, rest = t >> 9;
    int nt = rest & 7;
    int k = (l >> 4) * 8 + j, n = nt * 16 + (l & 15);
    val = (k < 10) ? h_w1[k * 128 + n] : 0.f;
  } else {                                  // Wh2: K=128, N=128
    int t = idx - OFF_WH2;
    int j = t & 7, l = (t >> 3) & 63, rest = t >> 9;
    int nt = rest & 7, ks = rest >> 3;
    int k = ks * 32 + (l >> 4) * 8 + j, n = nt * 16 + (l & 15);
    val = h_w2[k * 128 + n];
  }
  wsb[idx] = (__bf16)val;
}

// GEMM: M=64 (4 mtiles), waves split N. A in LDS (bf16, astride elems),
// B pre-swizzled in global: Bsw[((ks*NT_TOT + nt)*64 + lane)] is a bf16x8 frag.
template<int KSTEPS, int NT_TOT, int NTW>
__device__ __forceinline__ void run_gemm(const __bf16* A, int astride,
    const bf16x8* __restrict__ Bsw, int wave, int lane, f32x4 acc[4][NTW])
{
  const int quad = lane >> 4, ln = lane & 15;
  const int ntb = wave * NTW;
  bf16x8 bcur[NTW];
#pragma unroll
  for (int i = 0; i < NTW; ++i) bcur[i] = Bsw[(ntb + i) * 64 + lane];
#pragma unroll
  for (int ks = 0; ks < KSTEPS; ++ks) {
    bf16x8 bnxt[NTW];
    if (ks + 1 < KSTEPS) {
#pragma unroll
      for (int i = 0; i < NTW; ++i)
        bnxt[i] = Bsw[((ks + 1) * NT_TOT + ntb + i) * 64 + lane];
    }
    bf16x8 a[4];
#pragma unroll
    for (int mt = 0; mt < 4; ++mt)
      a[mt] = *(const bf16x8*)(A + (mt * 16 + ln) * astride + ks * 32 + quad * 8);
#pragma unroll
    for (int mt = 0; mt < 4; ++mt)
#pragma unroll
      for (int i = 0; i < NTW; ++i)
        acc[mt][i] = __builtin_amdgcn_mfma_f32_16x16x32_bf16(a[mt], bcur[i], acc[mt][i], 0, 0, 0);
    if (ks + 1 < KSTEPS) {
#pragma unroll
      for (int i = 0; i < NTW; ++i) bcur[i] = bnxt[i];
    }
  }
}

// bias + relu + LayerNorm(width W, split across 4 waves) -> bf16 LDS tile
template<int W, int NTW>
__device__ __forceinline__ void epilogue_ln(f32x4 acc[4][NTW],
    const float* __restrict__ bias, const float* __restrict__ g, const float* __restrict__ bb,
    __bf16* Adst, int dstride, int dstcol0,
    float* red_s, float* red_q, int wave, int lane)
{
  const int quad = lane >> 4, ln = lane & 15;
  float x[4][NTW][4];
#pragma unroll
  for (int i = 0; i < NTW; ++i) {
    int n = (wave * NTW + i) * 16 + ln;
    float b = bias[n];
#pragma unroll
    for (int mt = 0; mt < 4; ++mt)
#pragma unroll
      for (int r = 0; r < 4; ++r)
        x[mt][i][r] = fmaxf(acc[mt][i][r] + b, 0.f);
  }
#pragma unroll
  for (int mt = 0; mt < 4; ++mt) {
    float s[4] = {0, 0, 0, 0}, q[4] = {0, 0, 0, 0};
#pragma unroll
    for (int i = 0; i < NTW; ++i)
#pragma unroll
      for (int r = 0; r < 4; ++r) { s[r] += x[mt][i][r]; q[r] += x[mt][i][r] * x[mt][i][r]; }
#pragma unroll
    for (int m2 = 1; m2 < 16; m2 <<= 1)
#pragma unroll
      for (int r = 0; r < 4; ++r) {
        s[r] += __shfl_xor(s[r], m2, 64);
        q[r] += __shfl_xor(q[r], m2, 64);
      }
    if (ln == 0) {
#pragma unroll
      for (int r = 0; r < 4; ++r) {
        int m = mt * 16 + quad * 4 + r;
        red_s[wave * 64 + m] = s[r];
        red_q[wave * 64 + m] = q[r];
      }
    }
  }
  __syncthreads();
#pragma unroll
  for (int mt = 0; mt < 4; ++mt)
#pragma unroll
    for (int r = 0; r < 4; ++r) {
      int m = mt * 16 + quad * 4 + r;
      float tot = 0.f, totq = 0.f;
#pragma unroll
      for (int w2 = 0; w2 < 4; ++w2) { tot += red_s[w2 * 64 + m]; totq += red_q[w2 * 64 + m]; }
      float mu = tot / (float)W;
      float var = totq / (float)W - mu * mu;
      float rs = rsqrtf(var + 1e-5f);
#pragma unroll
      for (int i = 0; i < NTW; ++i) {
        int n = (wave * NTW + i) * 16 + ln;
        float o = (x[mt][i][r] - mu) * rs * g[n] + bb[n];
        Adst[m * dstride + dstcol0 + n] = (__bf16)o;
      }
    }
  __syncthreads();
}

__global__ __launch_bounds__(256) void critic_kernel(
    const float* __restrict__ obs, const float* __restrict__ pref,
    const float* __restrict__ h_b1, const float* __restrict__ h_g1, const float* __restrict__ h_bb1,
    const float* __restrict__ h_b2, const float* __restrict__ h_g2, const float* __restrict__ h_bb2,
    const float* __restrict__ p_w, const float* __restrict__ p_b,
    const float* __restrict__ p_g, const float* __restrict__ p_bb,
    const float* __restrict__ s_b1, const float* __restrict__ s_g1, const float* __restrict__ s_bb1,
    const float* __restrict__ s_b2, const float* __restrict__ s_g2, const float* __restrict__ s_bb2,
    const float* __restrict__ qd_b, const float* __restrict__ qe_b,
    const __bf16* __restrict__ wsb, float* __restrict__ out)
{
  // stride pads: 648 (=640+8), 264 (=256+8), 40 (=32+8) -> 2-way LDS aliasing only
  __shared__ __align__(16) __bf16 A_comb[64 * 648];  // 82944 B
  __shared__ __align__(16) __bf16 A_s[64 * 264];     // 33792 B
  __shared__ __align__(16) __bf16 A_h[64 * 40];      //  5120 B
  __shared__ float red_s[256];
  __shared__ float red_q[256];

  const int tid = threadIdx.x;
  const int wave = tid >> 6, lane = tid & 63;
  const int rowbase = blockIdx.x * 64;

  // ---------- front-end: each wave owns 16 rows ----------
  float pw0 = p_w[lane], pw1 = p_w[64 + lane], pb = p_b[lane];
  float pg = p_g[lane], pbb = p_bb[lane];
  for (int r = 0; r < 16; ++r) {
    int row = wave * 16 + r;
    int grow = rowbase + row;
    const float* orow = obs + (size_t)grow * 512;
    // obs_wo -> combined cols [0,448)
#pragma unroll
    for (int j = 0; j < 7; ++j) {
      int col = lane + 64 * j;
      int src = (col < 68) ? col : col + 64;
      A_comb[row * 648 + col] = (__bf16)orow[src];
    }
    // histogram of cols [68,132) via ballot
    float w = orow[68 + lane];
    int bi = (int)floorf(w);
    bi = bi < 0 ? 0 : (bi > 9 ? 9 : bi);
    bool valid = (w >= 0.f) && (w <= 10.f);
    float tot = 0.f, mine = 0.f;
#pragma unroll
    for (int b = 0; b < 10; ++b) {
      unsigned long long mk = __ballot(valid && (bi == b));
      float c = (float)__popcll(mk);
      tot += c;
      if (lane == b) mine = c;
    }
    float inv = 1.f / (tot + 1e-8f);
    if (lane < 32) A_h[row * 40 + lane] = (__bf16)((lane < 10) ? mine * inv : 0.f);
    // p layer: 2 -> 64, relu, LN over 64 lanes -> combined cols [576,640)
    float a0 = pref[grow * 2], a1 = pref[grow * 2 + 1];
    float v = fmaxf(fmaf(a0, pw0, fmaf(a1, pw1, pb)), 0.f);
    float s1 = v, s2 = v * v;
#pragma unroll
    for (int m2 = 1; m2 < 64; m2 <<= 1) {
      s1 += __shfl_xor(s1, m2, 64);
      s2 += __shfl_xor(s2, m2, 64);
    }
    float mu = s1 * (1.f / 64.f);
    float var = s2 * (1.f / 64.f) - mu * mu;
    float o = (v - mu) * rsqrtf(var + 1e-5f) * pg + pbb;
    A_comb[row * 648 + 576 + lane] = (__bf16)o;
  }
  __syncthreads();

  // ---------- h1: (64x32)@(32x128) ----------
  {
    f32x4 acc[4][2] = {};
    run_gemm<1, 8, 2>(A_h, 40, (const bf16x8*)(wsb + OFF_WH1), wave, lane, acc);
    epilogue_ln<128, 2>(acc, h_b1, h_g1, h_bb1, A_s, 264, 0, red_s, red_q, wave, lane);
  }
  // ---------- h2: (64x128)@(128x128) -> combined cols [448,576) ----------
  {
    f32x4 acc[4][2] = {};
    run_gemm<4, 8, 2>(A_s, 264, (const bf16x8*)(wsb + OFF_WH2), wave, lane, acc);
    epilogue_ln<128, 2>(acc, h_b2, h_g2, h_bb2, A_comb, 648, 448, red_s, red_q, wave, lane);
  }
  // ---------- s1: (64x640)@(640x256) ----------
  {
    f32x4 acc[4][4] = {};
    run_gemm<20, 16, 4>(A_comb, 648, (const bf16x8*)(wsb + OFF_W1), wave, lane, acc);
    epilogue_ln<256, 4>(acc, s_b1, s_g1, s_bb1, A_s, 264, 0, red_s, red_q, wave, lane);
  }
  // ---------- s2: (64x256)@(256x256), in-place (mid-epilogue barrier protects) ----------
  {
    f32x4 acc[4][4] = {};
    run_gemm<8, 16, 4>(A_s, 264, (const bf16x8*)(wsb + OFF_W2), wave, lane, acc);
    epilogue_ln<256, 4>(acc, s_b2, s_g2, s_bb2, A_s, 264, 0, red_s, red_q, wave, lane);
  }
  // ---------- q: (64x256)@(256x128), bias, store fp32 ----------
  {
    f32x4 acc[4][2] = {};
    run_gemm<8, 8, 2>(A_s, 264, (const bf16x8*)(wsb + OFF_WQ), wave, lane, acc);
    const int quad = lane >> 4, ln = lane & 15;
#pragma unroll
    for (int i = 0; i < 2; ++i) {
      int n = (wave * 2 + i) * 16 + ln;
      float qb = (n & 1) ? qe_b[n >> 1] : qd_b[n >> 1];
#pragma unroll
      for (int mt = 0; mt < 4; ++mt)
#pragma unroll
        for (int r = 0; r < 4; ++r) {
          int m = mt * 16 + quad * 4 + r;
          out[(size_t)(rowbase + m) * 128 + n] = acc[mt][i][r] + qb;
        }
    }
  }
}

extern "C" void kernel_launch(void* const* d_in, const int* in_sizes, int n_in,
                              void* d_out, int out_size, void* d_ws, size_t ws_size,
                              hipStream_t stream) {
  const float* obs    = (const float*)d_in[0];
  const float* pref   = (const float*)d_in[1];
  const float* h_w1   = (const float*)d_in[2];
  const float* h_b1   = (const float*)d_in[3];
  const float* h_g1   = (const float*)d_in[4];
  const float* h_bb1  = (const float*)d_in[5];
  const float* h_w2   = (const float*)d_in[6];
  const float* h_b2   = (const float*)d_in[7];
  const float* h_g2   = (const float*)d_in[8];
  const float* h_bb2  = (const float*)d_in[9];
  const float* p_w    = (const float*)d_in[10];
  const float* p_b    = (const float*)d_in[11];
  const float* p_g    = (const float*)d_in[12];
  const float* p_bb   = (const float*)d_in[13];
  const float* s_w1   = (const float*)d_in[14];
  const float* s_b1   = (const float*)d_in[15];
  const float* s_g1   = (const float*)d_in[16];
  const float* s_bb1  = (const float*)d_in[17];
  const float* s_w2   = (const float*)d_in[18];
  const float* s_b2   = (const float*)d_in[19];
  const float* s_g2   = (const float*)d_in[20];
  const float* s_bb2  = (const float*)d_in[21];
  const float* qd_w   = (const float*)d_in[22];
  const float* qd_b   = (const float*)d_in[23];
  const float* qe_w   = (const float*)d_in[24];
  const float* qe_b   = (const float*)d_in[25];

  __bf16* wsb = (__bf16*)d_ws;
  int B = in_sizes[0] / 512;
  int nblocks = B / 64;

  prep_kernel<<<(WS_ELEMS + 255) / 256, 256, 0, stream>>>(s_w1, s_w2, qd_w, qe_w, h_w1, h_w2, wsb);
  critic_kernel<<<nblocks, 256, 0, stream>>>(
      obs, pref, h_b1, h_g1, h_bb1, h_b2, h_g2, h_bb2,
      p_w, p_b, p_g, p_bb, s_b1, s_g1, s_bb1, s_b2, s_g2, s_bb2,
      qd_b, qe_b, (const __bf16*)wsb, (float*)d_out);
}

// Round 2
// 382.040 us; speedup vs baseline: 1.0726x; 1.0726x over previous
//
#include <hip/hip_runtime.h>

typedef __bf16 bf16x8 __attribute__((ext_vector_type(8)));
typedef float  f32x4  __attribute__((ext_vector_type(4)));

// ws layout (bf16 elements), all in MFMA b-fragment order [kstep][ntile][lane][8]
#define OFF_W1  0        // 20 ksteps * 16 nt * 512  = 163840   (s_w1 640x256)
#define OFF_W2  163840   //  8 * 16 * 512            =  65536   (s_w2 256x256)
#define OFF_WQ  229376   //  8 *  8 * 512            =  32768   (qd|qe interleaved 256x128)
#define OFF_WH1 262144   //  1 *  8 * 512            =   4096   (h_w1 10->32 zero-pad x128)
#define OFF_WH2 266240   //  4 *  8 * 512            =  16384   (h_w2 128x128)
#define WS_ELEMS 282624

__global__ __launch_bounds__(256) void prep_kernel(
    const float* __restrict__ s_w1, const float* __restrict__ s_w2,
    const float* __restrict__ qd_w, const float* __restrict__ qe_w,
    const float* __restrict__ h_w1, const float* __restrict__ h_w2,
    __bf16* __restrict__ wsb)
{
  int idx = blockIdx.x * 256 + threadIdx.x;
  if (idx >= WS_ELEMS) return;
  float val = 0.f;
  if (idx < OFF_W2) {                       // W1: K=640, N=256
    int t = idx;
    int j = t & 7, l = (t >> 3) & 63, rest = t >> 9;
    int nt = rest & 15, ks = rest >> 4;
    int k = ks * 32 + (l >> 4) * 8 + j, n = nt * 16 + (l & 15);
    val = s_w1[k * 256 + n];
  } else if (idx < OFF_WQ) {                // W2: K=256, N=256
    int t = idx - OFF_W2;
    int j = t & 7, l = (t >> 3) & 63, rest = t >> 9;
    int nt = rest & 15, ks = rest >> 4;
    int k = ks * 32 + (l >> 4) * 8 + j, n = nt * 16 + (l & 15);
    val = s_w2[k * 256 + n];
  } else if (idx < OFF_WH1) {               // Wq: K=256, N=128, n = 2a+sel
    int t = idx - OFF_WQ;
    int j = t & 7, l = (t >> 3) & 63, rest = t >> 9;
    int nt = rest & 7, ks = rest >> 3;
    int k = ks * 32 + (l >> 4) * 8 + j, n = nt * 16 + (l & 15);
    int a = n >> 1;
    val = (n & 1) ? qe_w[k * 64 + a] : qd_w[k * 64 + a];
  } else if (idx < OFF_WH2) {               // Wh1: K=10 padded to 32, N=128
    int t = idx - OFF_WH1;
    int j = t & 7, l = (t >> 3) & 63, rest = t >> 9;
    int nt = rest & 7;
    int k = (l >> 4) * 8 + j, n = nt * 16 + (l & 15);
    val = (k < 10) ? h_w1[k * 128 + n] : 0.f;
  } else {                                  // Wh2: K=128, N=128
    int t = idx - OFF_WH2;
    int j = t & 7, l = (t >> 3) & 63, rest = t >> 9;
    int nt = rest & 7, ks = rest >> 3;
    int k = ks * 32 + (l >> 4) * 8 + j, n = nt * 16 + (l & 15);
    val = h_w2[k * 128 + n];
  }
  wsb[idx] = (__bf16)val;
}

// 32 rows (2 mtiles), 8 waves split N. A in LDS bf16, B pre-swizzled in global.
template<int KSTEPS, int NT_TOT, int NTW>
__device__ __forceinline__ void run_gemm(const __bf16* A, int astride,
    const bf16x8* __restrict__ Bsw, int wave, int lane, f32x4 acc[2][NTW])
{
  const int quad = lane >> 4, ln = lane & 15;
  const int ntb = wave * NTW;
  bf16x8 bcur[NTW];
#pragma unroll
  for (int i = 0; i < NTW; ++i) bcur[i] = Bsw[(ntb + i) * 64 + lane];
#pragma unroll
  for (int ks = 0; ks < KSTEPS; ++ks) {
    bf16x8 bnxt[NTW];
    if (ks + 1 < KSTEPS) {
#pragma unroll
      for (int i = 0; i < NTW; ++i)
        bnxt[i] = Bsw[((ks + 1) * NT_TOT + ntb + i) * 64 + lane];
    }
    bf16x8 a[2];
#pragma unroll
    for (int mt = 0; mt < 2; ++mt)
      a[mt] = *(const bf16x8*)(A + (mt * 16 + ln) * astride + ks * 32 + quad * 8);
#pragma unroll
    for (int mt = 0; mt < 2; ++mt)
#pragma unroll
      for (int i = 0; i < NTW; ++i)
        acc[mt][i] = __builtin_amdgcn_mfma_f32_16x16x32_bf16(a[mt], bcur[i], acc[mt][i], 0, 0, 0);
    if (ks + 1 < KSTEPS) {
#pragma unroll
      for (int i = 0; i < NTW; ++i) bcur[i] = bnxt[i];
    }
  }
}

// bias + relu + LayerNorm(width W, split across 8 waves) -> bf16 LDS tile
template<int W, int NTW>
__device__ __forceinline__ void epilogue_ln(f32x4 acc[2][NTW],
    const float* __restrict__ bias, const float* __restrict__ g, const float* __restrict__ bb,
    __bf16* Adst, int dstride, int dstcol0,
    float* red_s, float* red_q, int wave, int lane)
{
  const int quad = lane >> 4, ln = lane & 15;
  float x[2][NTW][4];
#pragma unroll
  for (int i = 0; i < NTW; ++i) {
    int n = (wave * NTW + i) * 16 + ln;
    float b = bias[n];
#pragma unroll
    for (int mt = 0; mt < 2; ++mt)
#pragma unroll
      for (int r = 0; r < 4; ++r)
        x[mt][i][r] = fmaxf(acc[mt][i][r] + b, 0.f);
  }
#pragma unroll
  for (int mt = 0; mt < 2; ++mt) {
    float s[4] = {0, 0, 0, 0}, q[4] = {0, 0, 0, 0};
#pragma unroll
    for (int i = 0; i < NTW; ++i)
#pragma unroll
      for (int r = 0; r < 4; ++r) { s[r] += x[mt][i][r]; q[r] += x[mt][i][r] * x[mt][i][r]; }
#pragma unroll
    for (int m2 = 1; m2 < 16; m2 <<= 1)
#pragma unroll
      for (int r = 0; r < 4; ++r) {
        s[r] += __shfl_xor(s[r], m2, 64);
        q[r] += __shfl_xor(q[r], m2, 64);
      }
    if (ln == 0) {
#pragma unroll
      for (int r = 0; r < 4; ++r) {
        int m = mt * 16 + quad * 4 + r;
        red_s[wave * 32 + m] = s[r];
        red_q[wave * 32 + m] = q[r];
      }
    }
  }
  __syncthreads();
#pragma unroll
  for (int mt = 0; mt < 2; ++mt)
#pragma unroll
    for (int r = 0; r < 4; ++r) {
      int m = mt * 16 + quad * 4 + r;
      float tot = 0.f, totq = 0.f;
#pragma unroll
      for (int w2 = 0; w2 < 8; ++w2) { tot += red_s[w2 * 32 + m]; totq += red_q[w2 * 32 + m]; }
      float mu = tot / (float)W;
      float var = totq / (float)W - mu * mu;
      float rs = rsqrtf(var + 1e-5f);
#pragma unroll
      for (int i = 0; i < NTW; ++i) {
        int n = (wave * NTW + i) * 16 + ln;
        float o = (x[mt][i][r] - mu) * rs * g[n] + bb[n];
        Adst[m * dstride + dstcol0 + n] = (__bf16)o;
      }
    }
  __syncthreads();
}

__global__ __launch_bounds__(512, 4) void critic_kernel(
    const float* __restrict__ obs, const float* __restrict__ pref,
    const float* __restrict__ h_b1, const float* __restrict__ h_g1, const float* __restrict__ h_bb1,
    const float* __restrict__ h_b2, const float* __restrict__ h_g2, const float* __restrict__ h_bb2,
    const float* __restrict__ p_w, const float* __restrict__ p_b,
    const float* __restrict__ p_g, const float* __restrict__ p_bb,
    const float* __restrict__ s_b1, const float* __restrict__ s_g1, const float* __restrict__ s_bb1,
    const float* __restrict__ s_b2, const float* __restrict__ s_g2, const float* __restrict__ s_bb2,
    const float* __restrict__ qd_b, const float* __restrict__ qe_b,
    const __bf16* __restrict__ wsb, float* __restrict__ out)
{
  // 32 rows/block. stride pads keep 16B-aligned rows with odd 16B-stride (2-way free aliasing)
  __shared__ __align__(16) __bf16 A_comb[32 * 648];  // 41472 B
  __shared__ __align__(16) __bf16 A_s[32 * 264];     // 16896 B
  __shared__ __align__(16) __bf16 A_h[32 * 40];      //  2560 B
  __shared__ float red_s[256];
  __shared__ float red_q[256];

  const int tid = threadIdx.x;
  const int wave = tid >> 6, lane = tid & 63;
  const int rowbase = blockIdx.x * 32;

  // ---------- front-end: each of 8 waves owns 4 rows ----------
  float pw0 = p_w[lane], pw1 = p_w[64 + lane], pb = p_b[lane];
  float pg = p_g[lane], pbb = p_bb[lane];
#pragma unroll
  for (int r = 0; r < 4; ++r) {
    int row = wave * 4 + r;
    int grow = rowbase + row;
    const float* orow = obs + (size_t)grow * 512;
    // obs_wo -> combined cols [0,448)
#pragma unroll
    for (int j = 0; j < 7; ++j) {
      int col = lane + 64 * j;
      int src = (col < 68) ? col : col + 64;
      A_comb[row * 648 + col] = (__bf16)orow[src];
    }
    // histogram of cols [68,132) via ballot
    float w = orow[68 + lane];
    int bi = (int)floorf(w);
    bi = bi < 0 ? 0 : (bi > 9 ? 9 : bi);
    bool valid = (w >= 0.f) && (w <= 10.f);
    float tot = 0.f, mine = 0.f;
#pragma unroll
    for (int b = 0; b < 10; ++b) {
      unsigned long long mk = __ballot(valid && (bi == b));
      float c = (float)__popcll(mk);
      tot += c;
      if (lane == b) mine = c;
    }
    float inv = 1.f / (tot + 1e-8f);
    if (lane < 32) A_h[row * 40 + lane] = (__bf16)((lane < 10) ? mine * inv : 0.f);
    // p layer: 2 -> 64, relu, LN over 64 lanes -> combined cols [576,640)
    float a0 = pref[grow * 2], a1 = pref[grow * 2 + 1];
    float v = fmaxf(fmaf(a0, pw0, fmaf(a1, pw1, pb)), 0.f);
    float s1 = v, s2 = v * v;
#pragma unroll
    for (int m2 = 1; m2 < 64; m2 <<= 1) {
      s1 += __shfl_xor(s1, m2, 64);
      s2 += __shfl_xor(s2, m2, 64);
    }
    float mu = s1 * (1.f / 64.f);
    float var = s2 * (1.f / 64.f) - mu * mu;
    float o = (v - mu) * rsqrtf(var + 1e-5f) * pg + pbb;
    A_comb[row * 648 + 576 + lane] = (__bf16)o;
  }
  __syncthreads();

  // ---------- h1: (32x32)@(32x128) ----------
  {
    f32x4 acc[2][1] = {};
    run_gemm<1, 8, 1>(A_h, 40, (const bf16x8*)(wsb + OFF_WH1), wave, lane, acc);
    epilogue_ln<128, 1>(acc, h_b1, h_g1, h_bb1, A_s, 264, 0, red_s, red_q, wave, lane);
  }
  // ---------- h2: (32x128)@(128x128) -> combined cols [448,576) ----------
  {
    f32x4 acc[2][1] = {};
    run_gemm<4, 8, 1>(A_s, 264, (const bf16x8*)(wsb + OFF_WH2), wave, lane, acc);
    epilogue_ln<128, 1>(acc, h_b2, h_g2, h_bb2, A_comb, 648, 448, red_s, red_q, wave, lane);
  }
  // ---------- s1: (32x640)@(640x256) ----------
  {
    f32x4 acc[2][2] = {};
    run_gemm<20, 16, 2>(A_comb, 648, (const bf16x8*)(wsb + OFF_W1), wave, lane, acc);
    epilogue_ln<256, 2>(acc, s_b1, s_g1, s_bb1, A_s, 264, 0, red_s, red_q, wave, lane);
  }
  // ---------- s2: (32x256)@(256x256), in-place (epilogue barrier protects) ----------
  {
    f32x4 acc[2][2] = {};
    run_gemm<8, 16, 2>(A_s, 264, (const bf16x8*)(wsb + OFF_W2), wave, lane, acc);
    epilogue_ln<256, 2>(acc, s_b2, s_g2, s_bb2, A_s, 264, 0, red_s, red_q, wave, lane);
  }
  // ---------- q: (32x256)@(256x128), bias, store fp32 ----------
  {
    f32x4 acc[2][1] = {};
    run_gemm<8, 8, 1>(A_s, 264, (const bf16x8*)(wsb + OFF_WQ), wave, lane, acc);
    const int quad = lane >> 4, ln = lane & 15;
    int n = wave * 16 + ln;
    float qb = (n & 1) ? qe_b[n >> 1] : qd_b[n >> 1];
#pragma unroll
    for (int mt = 0; mt < 2; ++mt)
#pragma unroll
      for (int r = 0; r < 4; ++r) {
        int m = mt * 16 + quad * 4 + r;
        out[(size_t)(rowbase + m) * 128 + n] = acc[mt][0][r] + qb;
      }
  }
}

extern "C" void kernel_launch(void* const* d_in, const int* in_sizes, int n_in,
                              void* d_out, int out_size, void* d_ws, size_t ws_size,
                              hipStream_t stream) {
  const float* obs    = (const float*)d_in[0];
  const float* pref   = (const float*)d_in[1];
  const float* h_w1   = (const float*)d_in[2];
  const float* h_b1   = (const float*)d_in[3];
  const float* h_g1   = (const float*)d_in[4];
  const float* h_bb1  = (const float*)d_in[5];
  const float* h_w2   = (const float*)d_in[6];
  const float* h_b2   = (const float*)d_in[7];
  const float* h_g2   = (const float*)d_in[8];
  const float* h_bb2  = (const float*)d_in[9];
  const float* p_w    = (const float*)d_in[10];
  const float* p_b    = (const float*)d_in[11];
  const float* p_g    = (const float*)d_in[12];
  const float* p_bb   = (const float*)d_in[13];
  const float* s_w1   = (const float*)d_in[14];
  const float* s_b1   = (const float*)d_in[15];
  const float* s_g1   = (const float*)d_in[16];
  const float* s_bb1  = (const float*)d_in[17];
  const float* s_w2   = (const float*)d_in[18];
  const float* s_b2   = (const float*)d_in[19];
  const float* s_g2   = (const float*)d_in[20];
  const float* s_bb2  = (const float*)d_in[21];
  const float* qd_w   = (const float*)d_in[22];
  const float* qd_b   = (const float*)d_in[23];
  const float* qe_w   = (const float*)d_in[24];
  const float* qe_b   = (const float*)d_in[25];

  __bf16* wsb = (__bf16*)d_ws;
  int B = in_sizes[0] / 512;
  int nblocks = B / 32;

  prep_kernel<<<(WS_ELEMS + 255) / 256, 256, 0, stream>>>(s_w1, s_w2, qd_w, qe_w, h_w1, h_w2, wsb);
  critic_kernel<<<nblocks, 512, 0, stream>>>(
      obs, pref, h_b1, h_g1, h_bb1, h_b2, h_g2, h_bb2,
      p_w, p_b, p_g, p_bb, s_b1, s_g1, s_bb1, s_b2, s_g2, s_bb2,
      qd_b, qe_b, (const __bf16*)wsb, (float*)d_out);
}